// Round 8
// baseline (660.531 us; speedup 1.0000x reference)
//
#include <hip/hip_runtime.h>

#define NCC 617
#define TTT 15
#define FFF 5
#define SSN 200000
#define EEN 1000000
#define ECN 20000
#define CSBLK 196   /* ceil(SSN/1024) */
#define NB2 512
#define EPB2 ((EEN + NB2 - 1) / NB2)   /* 1954 */
#define ZN (NCC + NCC + SSN + SSN)
#define HALLB ((ECN + EEN + 255) / 256) /* 3985 */
#define SGB 782     /* ceil(SSN/256) sentence-gin blocks */
#define LSTMB ((NCC + 15) / 16)         /* 39 */

typedef unsigned short u16;
typedef unsigned int   u32;

using short8  = __attribute__((ext_vector_type(8))) short;
using f32x4v  = __attribute__((ext_vector_type(4))) float;

__device__ __forceinline__ float bf2f(u16 u){ return __uint_as_float(((u32)u) << 16); }
__device__ __forceinline__ u16 f2bf(float f){
  u32 x = __float_as_uint(f);
  u32 r = (x + 0x7fffu + ((x >> 16) & 1u)) >> 16;
  return (u16)r;
}
__device__ __forceinline__ u32 pk2(float a, float b){ return (u32)f2bf(a) | ((u32)f2bf(b) << 16); }
__device__ __forceinline__ float sigm(float x){ return 1.0f / (1.0f + __expf(-x)); }

// ---------------- zero counters ----------------
__global__ __launch_bounds__(256) void k_zero(int* p, int n){
  int i = blockIdx.x * 256 + threadIdx.x;
  if (i < n) p[i] = 0;
}

// ---------------- fused histograms: s2c LDS block-hist | c2c+c2s global-atomic hist ----------------
__global__ __launch_bounds__(256) void k_histF(const int* __restrict__ s2c_dst, int* __restrict__ blockHist,
                                               const int* __restrict__ c2c_dst, int* __restrict__ cnt_c2c,
                                               const int* __restrict__ c2s_dst, int* __restrict__ cnt_c2s){
  __shared__ int h[NCC];
  int b = blockIdx.x, tid = threadIdx.x;
  if (b < NB2){
    for (int i = tid; i < NCC; i += 256) h[i] = 0;
    __syncthreads();
    int e0 = b * EPB2;
    int e1 = e0 + EPB2; if (e1 > EEN) e1 = EEN;
    for (int e = e0 + tid; e < e1; e += 256) atomicAdd(&h[s2c_dst[e]], 1);
    __syncthreads();
    for (int i = tid; i < NCC; i += 256) blockHist[i * NB2 + b] = h[i];
  } else {
    int i = (b - NB2) * 256 + tid;
    if (i < ECN) atomicAdd(&cnt_c2c[c2c_dst[i]], 1);
    else if (i < ECN + EEN) atomicAdd(&cnt_c2s[c2s_dst[i - ECN]], 1);
  }
}

// ---------------- fused: colscan (617) | c2s block-scan (196) | batchnorm (15) ----------------
__global__ __launch_bounds__(1024) void k_scanA(int* __restrict__ blockHist, int* __restrict__ colTotal,
                                                const int* __restrict__ cnt_c2s, int* __restrict__ off_c2s,
                                                int* __restrict__ bsum,
                                                const float* __restrict__ ts, const float* __restrict__ gamma,
                                                const float* __restrict__ beta, float* __restrict__ tsn){
  __shared__ int buf[1024];
  __shared__ float ss[1024], s2[1024];
  int b = blockIdx.x, tid = threadIdx.x;
  if (b < NCC){
    if (tid < 64){
      int lane = tid;
      int base = 0;
      for (int j = 0; j < NB2; j += 64){
        int v = blockHist[b * NB2 + j + lane];
        int orig = v;
        #pragma unroll
        for (int s = 1; s < 64; s <<= 1){
          int t = __shfl_up(v, s, 64);
          if (lane >= s) v += t;
        }
        blockHist[b * NB2 + j + lane] = base + v - orig;
        base += __shfl(v, 63, 64);
      }
      if (lane == 0) colTotal[b] = base;
    }
  } else if (b < NCC + CSBLK) {
    int bb = b - NCC;
    int gi = bb * 1024 + tid;
    int v = (gi < SSN) ? cnt_c2s[gi] : 0;
    buf[tid] = v;
    __syncthreads();
    for (int d = 1; d < 1024; d <<= 1){
      int x = (tid >= d) ? buf[tid - d] : 0;
      __syncthreads();
      buf[tid] += x;
      __syncthreads();
    }
    if (gi < SSN) off_c2s[gi] = buf[tid] - v;
    if (tid == 1023) bsum[bb] = buf[1023];
  } else {
    int t = b - (NCC + CSBLK);
    float a = 0.f, s = 0.f;
    for (int c = tid; c < NCC; c += 1024){
      float v = ts[(c * TTT + t) * FFF + 3];
      a += v; s += v * v;
    }
    ss[tid] = a; s2[tid] = s;
    __syncthreads();
    for (int d = 512; d > 0; d >>= 1){
      if (tid < d){ ss[tid] += ss[tid + d]; s2[tid] += s2[tid + d]; }
      __syncthreads();
    }
    float mean = ss[0] / (float)NCC;
    float var  = s2[0] / (float)NCC - mean * mean;
    float rstd = rsqrtf(var + 1e-5f);
    float g = gamma[t], be = beta[t];
    for (int c = tid; c < NCC; c += 1024){
      float v = ts[(c * TTT + t) * FFF + 3];
      tsn[c * TTT + t] = (v - mean) * rstd * g + be;
    }
  }
}

// ================ fused: dual 617-scan (b0) | c2s scan-add (b1..196) | 2-layer LSTM (b197..235) ================
__global__ __launch_bounds__(1024) void k_scanBL(const int* __restrict__ cnt_c2c, int* __restrict__ off_c2c,
                                                 const int* __restrict__ colTotal, int* __restrict__ off_s2c,
                                                 int* __restrict__ off_c2s, const int* __restrict__ bsum,
                                                 const float* __restrict__ tsn,
                                                 const float* __restrict__ Wih0, const float* __restrict__ Whh0,
                                                 const float* __restrict__ bih0, const float* __restrict__ bhh0,
                                                 const float* __restrict__ Wih1, const float* __restrict__ Whh1,
                                                 const float* __restrict__ bih1, const float* __restrict__ bhh1,
                                                 const float* __restrict__ fcW, const float* __restrict__ fcb,
                                                 const float* __restrict__ emb, const int* __restrict__ ids,
                                                 float* __restrict__ comp0){
  __shared__ __align__(16) u16 sW0[64 * 64 * 4];   // 32 KB (reused as buf/sboff/fws)
  __shared__ __align__(16) u16 sP1[64 * 64 * 8];   // 64 KB
  __shared__ float sWi[256];
  __shared__ float sB0[256];
  int b = blockIdx.x, tid = threadIdx.x;
  if (b == 0){
    int* buf = (int*)sW0;
    for (int pass = 0; pass < 2; ++pass){
      const int* cnt = pass ? colTotal : cnt_c2c;
      int* ofs = pass ? off_s2c : off_c2c;
      int v = (tid < NCC) ? cnt[tid] : 0;
      buf[tid] = v;
      __syncthreads();
      for (int d = 1; d < 1024; d <<= 1){
        int x = (tid >= d) ? buf[tid - d] : 0;
        __syncthreads();
        buf[tid] += x;
        __syncthreads();
      }
      if (tid < NCC) ofs[tid] = (tid == 0) ? 0 : buf[tid - 1];
      if (tid == 0) ofs[NCC] = buf[NCC - 1];
      __syncthreads();
    }
  } else if (b <= CSBLK){
    int* sboff = (int*)sW0;
    int bb = b - 1;
    int lane = tid & 63;
    if (tid < 64){
      int base = 0;
      for (int j = 0; j < CSBLK; j += 64){
        int idx = j + lane;
        int v = (idx < CSBLK) ? bsum[idx] : 0;
        int orig = v;
        #pragma unroll
        for (int s = 1; s < 64; s <<= 1){
          int t2 = __shfl_up(v, s, 64);
          if (lane >= s) v += t2;
        }
        if (idx < CSBLK) sboff[idx] = base + v - orig;
        base += __shfl(v, 63, 64);
      }
      if (lane == 0) sboff[CSBLK] = base;
    }
    __syncthreads();
    int gi = bb * 1024 + tid;
    if (gi < SSN) off_c2s[gi] += sboff[bb];
    if (bb == 0 && tid == 0) off_c2s[SSN] = sboff[CSBLK];
  } else {
    // ---- fused 2-layer LSTM + fc + emb, 16 companies/block ----
    int bb = b - (CSBLK + 1);
    for (int i = tid; i < 16384; i += 1024){
      int k = i >> 8, j = (i >> 2) & 63, g = i & 3;
      sW0[i] = f2bf(Whh0[(g * 64 + j) * 64 + k]);
    }
    for (int i = tid; i < 32768; i += 1024){
      int k = i >> 9, j = (i >> 3) & 63, g = i & 7;
      float v = (g < 4) ? Wih1[(g * 64 + j) * 64 + k] : Whh1[((g - 4) * 64 + j) * 64 + k];
      sP1[i] = f2bf(v);
    }
    if (tid < 256){
      sWi[tid] = Wih0[tid];
      sB0[tid] = bih0[tid] + bhh0[tid];
    }
    __syncthreads();
    int wave = tid >> 6, lane = tid & 63;
    int c = bb * 16 + wave;
    int ci = (c < NCC) ? c : (NCC - 1);
    float wi_i = sWi[lane], wi_f = sWi[64 + lane], wi_g = sWi[128 + lane], wi_o = sWi[192 + lane];
    float b0i = sB0[lane], b0f = sB0[64 + lane], b0g = sB0[128 + lane], b0o = sB0[192 + lane];
    float b1i = bih1[lane]       + bhh1[lane];
    float b1f = bih1[64 + lane]  + bhh1[64 + lane];
    float b1g = bih1[128 + lane] + bhh1[128 + lane];
    float b1o = bih1[192 + lane] + bhh1[192 + lane];
    float h0 = 0.f, c0 = 0.f, h1 = 0.f, c1 = 0.f;
    for (int t = 0; t < TTT; ++t){
      float x = tsn[ci * TTT + t];
      float gi = b0i + x * wi_i, gf = b0f + x * wi_f, gg = b0g + x * wi_g, go = b0o + x * wi_o;
      #pragma unroll 4
      for (int k = 0; k < 64; ++k){
        float hk = __shfl(h0, k, 64);
        ushort4 w = *(const ushort4*)&sW0[(k * 64 + lane) * 4];
        gi += hk * bf2f(w.x); gf += hk * bf2f(w.y);
        gg += hk * bf2f(w.z); go += hk * bf2f(w.w);
      }
      c0 = sigm(gf) * c0 + sigm(gi) * tanhf(gg);
      h0 = sigm(go) * tanhf(c0);
      gi = b1i; gf = b1f; gg = b1g; go = b1o;
      #pragma unroll 4
      for (int k = 0; k < 64; ++k){
        float xk = __shfl(h0, k, 64);
        float hk = __shfl(h1, k, 64);
        short8 wv = *(const short8*)&sP1[(k * 64 + lane) * 8];
        gi += xk * bf2f((u16)wv[0]) + hk * bf2f((u16)wv[4]);
        gf += xk * bf2f((u16)wv[1]) + hk * bf2f((u16)wv[5]);
        gg += xk * bf2f((u16)wv[2]) + hk * bf2f((u16)wv[6]);
        go += xk * bf2f((u16)wv[3]) + hk * bf2f((u16)wv[7]);
      }
      c1 = sigm(gf) * c1 + sigm(gi) * tanhf(gg);
      h1 = sigm(go) * tanhf(c1);
    }
    __syncthreads();
    float* fws = (float*)sW0;
    for (int i = tid; i < 4096; i += 1024){
      int d = i >> 6, k = i & 63;
      fws[k * 64 + d] = fcW[i];
    }
    __syncthreads();
    float y = fcb[lane];
    #pragma unroll 4
    for (int k = 0; k < 64; ++k){
      float hk = __shfl(h1, k, 64);
      y += hk * fws[k * 64 + lane];
    }
    y = fmaxf(y, 0.f);
    if (c < NCC) comp0[c * 64 + lane] = y + emb[ids[c] * 64 + lane];
  }
}

// ---------------- fused scatter ----------------
__global__ __launch_bounds__(256) void k_scatF(const int* __restrict__ s2c_src, const int* __restrict__ s2c_dst,
                                               const int* __restrict__ blockHist, const int* __restrict__ off_s2c,
                                               int* __restrict__ bkt_s2c,
                                               const int* __restrict__ c2c_src, const int* __restrict__ c2c_dst,
                                               const int* __restrict__ off_c2c, int* __restrict__ cnt2_c2c,
                                               int* __restrict__ bkt_c2c,
                                               const int* __restrict__ c2s_src, const int* __restrict__ c2s_dst,
                                               const int* __restrict__ off_c2s, int* __restrict__ cnt2_c2s,
                                               int* __restrict__ bkt_c2s){
  __shared__ int cur[NCC];
  int b = blockIdx.x, tid = threadIdx.x;
  if (b < NB2){
    for (int i = tid; i < NCC; i += 256) cur[i] = off_s2c[i] + blockHist[i * NB2 + b];
    __syncthreads();
    int e0 = b * EPB2;
    int e1 = e0 + EPB2; if (e1 > EEN) e1 = EEN;
    for (int e = e0 + tid; e < e1; e += 256){
      int d = s2c_dst[e];
      int p = atomicAdd(&cur[d], 1);
      bkt_s2c[p] = s2c_src[e];
    }
  } else {
    int i = (b - NB2) * 256 + tid;
    if (i < ECN){
      int d = c2c_dst[i]; int p = off_c2c[d] + atomicAdd(&cnt2_c2c[d], 1); bkt_c2c[p] = c2c_src[i];
    } else if (i < ECN + EEN){
      int k = i - ECN;
      int d = c2s_dst[k]; int p = off_c2s[d] + atomicAdd(&cnt2_c2s[d], 1); bkt_c2s[p] = c2s_src[k];
    }
  }
}

// ---------------- proj GEMM via MFMA ----------------
__global__ __launch_bounds__(256) void k_projm(const float* __restrict__ A, const float* __restrict__ W,
                                               const float* __restrict__ pb, u16* __restrict__ sent0){
  __shared__ __align__(16) u16 sA[128 * 64];
  __shared__ __align__(16) u16 sB[64 * 64];
  char* sAb = (char*)sA;
  char* sBb = (char*)sB;
  int tid = threadIdx.x;
  int wave = tid >> 6, lane = tid & 63;
  int l15 = lane & 15, lg = lane >> 4;
  int s0 = blockIdx.x * 128;

  int rA = tid >> 1, hA = tid & 1;
  int sA_row = s0 + rA; if (sA_row >= SSN) sA_row = SSN - 1;
  const float* gA0 = &A[(size_t)sA_row * 768 + hA * 32];
  u32 aw_base = (u32)(rA * 128 + hA * 64);
  u32 aw_swz  = (u32)((rA & 7) << 4);
  int nB = tid >> 2, qB = tid & 3;
  const float* gB0 = &W[(size_t)nB * 768 + qB * 16];
  u32 bw_base = (u32)(nB * 128 + qB * 32);
  u32 bw_swz  = (u32)((nB & 7) << 4);

  int arow = wave * 32 + l15;
  u32 ar_swz = (u32)((arow & 7) << 4);
  u32 ar_base = (u32)(arow * 128 + lg * 16);
  u32 br_swz = (u32)((l15 & 7) << 4);
  u32 br_base = (u32)(l15 * 128 + lg * 16);

  f32x4v acc[2][4] = {};

  for (int kc = 0; kc < 12; ++kc){
    __syncthreads();
    {
      const float* g = gA0 + kc * 64;
      #pragma unroll
      for (int q = 0; q < 4; ++q){
        float4 va = ((const float4*)g)[2 * q];
        float4 vb = ((const float4*)g)[2 * q + 1];
        uint4 w;
        w.x = pk2(va.x, va.y); w.y = pk2(va.z, va.w);
        w.z = pk2(vb.x, vb.y); w.w = pk2(vb.z, vb.w);
        *(uint4*)(sAb + ((aw_base + q * 16) ^ aw_swz)) = w;
      }
    }
    {
      const float* g = gB0 + kc * 64;
      #pragma unroll
      for (int q = 0; q < 2; ++q){
        float4 va = ((const float4*)g)[2 * q];
        float4 vb = ((const float4*)g)[2 * q + 1];
        uint4 w;
        w.x = pk2(va.x, va.y); w.y = pk2(va.z, va.w);
        w.z = pk2(vb.x, vb.y); w.w = pk2(vb.z, vb.w);
        *(uint4*)(sBb + ((bw_base + q * 16) ^ bw_swz)) = w;
      }
    }
    __syncthreads();
    #pragma unroll
    for (int ks = 0; ks < 2; ++ks){
      short8 a0 = *(const short8*)(sAb + ((ar_base + 0    + ks * 64) ^ ar_swz));
      short8 a1 = *(const short8*)(sAb + ((ar_base + 2048 + ks * 64) ^ ar_swz));
      short8 b0 = *(const short8*)(sBb + ((br_base + 0    + ks * 64) ^ br_swz));
      short8 b1 = *(const short8*)(sBb + ((br_base + 2048 + ks * 64) ^ br_swz));
      short8 b2 = *(const short8*)(sBb + ((br_base + 4096 + ks * 64) ^ br_swz));
      short8 b3 = *(const short8*)(sBb + ((br_base + 6144 + ks * 64) ^ br_swz));
      acc[0][0] = __builtin_amdgcn_mfma_f32_16x16x32_bf16(a0, b0, acc[0][0], 0, 0, 0);
      acc[0][1] = __builtin_amdgcn_mfma_f32_16x16x32_bf16(a0, b1, acc[0][1], 0, 0, 0);
      acc[0][2] = __builtin_amdgcn_mfma_f32_16x16x32_bf16(a0, b2, acc[0][2], 0, 0, 0);
      acc[0][3] = __builtin_amdgcn_mfma_f32_16x16x32_bf16(a0, b3, acc[0][3], 0, 0, 0);
      acc[1][0] = __builtin_amdgcn_mfma_f32_16x16x32_bf16(a1, b0, acc[1][0], 0, 0, 0);
      acc[1][1] = __builtin_amdgcn_mfma_f32_16x16x32_bf16(a1, b1, acc[1][1], 0, 0, 0);
      acc[1][2] = __builtin_amdgcn_mfma_f32_16x16x32_bf16(a1, b2, acc[1][2], 0, 0, 0);
      acc[1][3] = __builtin_amdgcn_mfma_f32_16x16x32_bf16(a1, b3, acc[1][3], 0, 0, 0);
    }
  }

  float bias[4];
  #pragma unroll
  for (int nt = 0; nt < 4; ++nt) bias[nt] = pb[nt * 16 + l15];
  #pragma unroll
  for (int mt = 0; mt < 2; ++mt){
    #pragma unroll
    for (int j = 0; j < 4; ++j){
      int s = s0 + wave * 32 + mt * 16 + lg * 4 + j;
      if (s < SSN){
        #pragma unroll
        for (int nt = 0; nt < 4; ++nt)
          sent0[(size_t)s * 64 + nt * 16 + l15] = f2bf(acc[mt][nt][j] + bias[nt]);
      }
    }
  }
}

// ---------------- merged GIN layer 0 ----------------
__global__ __launch_bounds__(1024) void k_gin0(const float* __restrict__ compIn, const u16* __restrict__ sentIn,
                                               const int* __restrict__ ofsA, const int* __restrict__ bktA,
                                               const int* __restrict__ ofsB, const int* __restrict__ bktB,
                                               const int* __restrict__ ofsS, const int* __restrict__ bktS,
                                               const float* __restrict__ gin_W, const float* __restrict__ gin_b,
                                               const float* __restrict__ gin_a,
                                               float* __restrict__ compOut, u16* __restrict__ sentOut){
  __shared__ __align__(16) char smem[52224];
  int tid = threadIdx.x;
  int wave = tid >> 6, lane = tid & 63;
  int b = blockIdx.x;
  if (b < NCC){
    float* Wat  = (float*)smem;
    float* Wbt  = Wat + 64 * 68;
    int*   eidx = (int*)(Wbt + 64 * 68);
    float* part = (float*)(eidx + 2048);
    float* xa   = part + 2048;
    float* xb   = xa + 64;
    float* outab = xb + 64;
    const float* Wa = gin_W + 0 * 4096;
    const float* Wb = gin_W + 1 * 4096;
    for (int i = tid; i < 4096; i += 1024){
      int j = i >> 6, k = i & 63;
      Wat[k * 68 + j] = Wa[i];
      Wbt[k * 68 + j] = Wb[i];
    }
    int c = b;
    float accA = 0.f, accB = 0.f;
    int a0 = ofsA[c], a1 = ofsA[c + 1];
    for (int base = a0; base < a1; base += 2048){
      int cnt = a1 - base; if (cnt > 2048) cnt = 2048;
      __syncthreads();
      for (int i = tid; i < cnt; i += 1024) eidx[i] = bktA[base + i];
      __syncthreads();
      #pragma unroll 4
      for (int i = wave; i < cnt; i += 16) accA += compIn[eidx[i] * 64 + lane];
    }
    int b0 = ofsB[c], b1 = ofsB[c + 1];
    for (int base = b0; base < b1; base += 2048){
      int cnt = b1 - base; if (cnt > 2048) cnt = 2048;
      __syncthreads();
      for (int i = tid; i < cnt; i += 1024) eidx[i] = bktB[base + i];
      __syncthreads();
      #pragma unroll 8
      for (int i = wave; i < cnt; i += 16) accB += bf2f(sentIn[(size_t)eidx[i] * 64 + lane]);
    }
    part[(wave * 2 + 0) * 64 + lane] = accA;
    part[(wave * 2 + 1) * 64 + lane] = accB;
    __syncthreads();
    if (tid < 128){
      int l = tid & 63, which = tid >> 6;
      float m = 0.f;
      #pragma unroll
      for (int w = 0; w < 16; ++w) m += part[(w * 2 + which) * 64 + l];
      float ci = compIn[c * 64 + l];
      if (which == 0) xa[l] = ci + m; else xb[l] = ci + m;
    }
    __syncthreads();
    if (tid < 128){
      int j = tid & 63;
      const float* X  = (tid < 64) ? xa : xb;
      const float* Wt = (tid < 64) ? Wat : Wbt;
      float acc = (tid < 64) ? gin_b[j] : gin_b[64 + j];
      #pragma unroll 4
      for (int k = 0; k < 64; ++k) acc += X[k] * Wt[k * 68 + j];
      float al = (tid < 64) ? gin_a[0] : gin_a[1];
      outab[tid] = (acc >= 0.f) ? acc : al * acc;
    }
    __syncthreads();
    if (tid < 64) compOut[c * 64 + tid] = outab[tid] + outab[64 + tid];
  } else {
    u16* sX   = (u16*)smem;
    u16* sW   = sX + 16384;
    int* eb   = (int*)(sW + 4096);
    int* sofs = eb + 2048;
    char* sXb = (char*)sX;
    char* sWb = (char*)sW;
    const float* W = gin_W + 2 * 4096;
    const float* bi = gin_b + 128;
    {
      int n = tid >> 4, q = tid & 15;
      float4 v = *(const float4*)&W[n * 64 + q * 4];
      uint2 w;
      w.x = pk2(v.x, v.y); w.y = pk2(v.z, v.w);
      *(uint2*)(sWb + (((u32)(n * 128 + q * 8)) ^ ((u32)((n & 7) << 4)))) = w;
    }
    int sBase = (b - NCC) * 256;
    if (tid < 257){
      int idx = sBase + tid; if (idx > SSN) idx = SSN;
      sofs[tid] = ofsS[idx];
    }
    __syncthreads();
    int E0 = sofs[0];
    int tot = sofs[256] - E0;
    int staged = tot < 2048 ? tot : 2048;
    for (int i = tid; i < staged; i += 1024) eb[i] = bktS[E0 + i];
    __syncthreads();
    for (int q = 0; q < 16; ++q){
      int sL = wave * 16 + q;
      int s = sBase + sL;
      if (s < SSN){
        float acc = bf2f(sentIn[(size_t)s * 64 + lane]);
        int e0 = sofs[sL], e1 = sofs[sL + 1];
        for (int e = e0; e < e1; ++e){
          int r = e - E0;
          int src = (r < 2048) ? eb[r] : bktS[e];
          acc += compIn[src * 64 + lane];
        }
        *(u16*)(sXb + (((u32)(sL * 128 + lane * 2)) ^ ((u32)((sL & 7) << 4)))) = f2bf(acc);
      }
    }
    __syncthreads();
    int l15 = lane & 15, lg = lane >> 4;
    int arow = wave * 16 + l15;
    u32 ar_swz = (u32)((arow & 7) << 4);
    u32 br_swz = (u32)((l15 & 7) << 4);
    f32x4v acc4[4] = {};
    #pragma unroll
    for (int ks = 0; ks < 2; ++ks){
      short8 a0 = *(const short8*)(sXb + (((u32)(arow * 128 + ks * 64 + lg * 16)) ^ ar_swz));
      #pragma unroll
      for (int nt = 0; nt < 4; ++nt){
        short8 b0 = *(const short8*)(sWb + (((u32)((nt * 16 + l15) * 128 + ks * 64 + lg * 16)) ^ br_swz));
        acc4[nt] = __builtin_amdgcn_mfma_f32_16x16x32_bf16(a0, b0, acc4[nt], 0, 0, 0);
      }
    }
    float alpha = gin_a[2];
    #pragma unroll
    for (int nt = 0; nt < 4; ++nt){
      float bb = bi[nt * 16 + l15];
      #pragma unroll
      for (int j = 0; j < 4; ++j){
        int srow = sBase + wave * 16 + lg * 4 + j;
        if (srow < SSN){
          float h = acc4[nt][j] + bb;
          h = (h >= 0.f) ? h : alpha * h;
          sentOut[(size_t)srow * 64 + nt * 16 + l15] = f2bf(h);
        }
      }
    }
  }
}

// ---------------- company GIN layer 1 + fused classifier ----------------
__global__ __launch_bounds__(1024) void k_cgin1(const float* __restrict__ compIn, const u16* __restrict__ sentIn,
                                                const int* __restrict__ ofsA, const int* __restrict__ bktA,
                                                const int* __restrict__ ofsB, const int* __restrict__ bktB,
                                                const float* __restrict__ Wa, const float* __restrict__ ba, const float* aaP,
                                                const float* __restrict__ Wb, const float* __restrict__ bb, const float* abP,
                                                const float* __restrict__ clsW, const float* __restrict__ clsb,
                                                float* __restrict__ outp){
  __shared__ __align__(16) float Wat[64 * 68];
  __shared__ __align__(16) float Wbt[64 * 68];
  __shared__ int eidx[2048];
  __shared__ float part[16][2][64];
  __shared__ float xa[64], xb[64], outab[128];
  int tid = threadIdx.x;
  for (int i = tid; i < 4096; i += 1024){
    int j = i >> 6, k = i & 63;
    Wat[k * 68 + j] = Wa[i];
    Wbt[k * 68 + j] = Wb[i];
  }
  int wave = tid >> 6, lane = tid & 63;
  int c = blockIdx.x;
  float accA = 0.f, accB = 0.f;
  int a0 = ofsA[c], a1 = ofsA[c + 1];
  for (int base = a0; base < a1; base += 2048){
    int cnt = a1 - base; if (cnt > 2048) cnt = 2048;
    __syncthreads();
    for (int i = tid; i < cnt; i += 1024) eidx[i] = bktA[base + i];
    __syncthreads();
    #pragma unroll 4
    for (int i = wave; i < cnt; i += 16) accA += compIn[eidx[i] * 64 + lane];
  }
  int b0 = ofsB[c], b1 = ofsB[c + 1];
  for (int base = b0; base < b1; base += 2048){
    int cnt = b1 - base; if (cnt > 2048) cnt = 2048;
    __syncthreads();
    for (int i = tid; i < cnt; i += 1024) eidx[i] = bktB[base + i];
    __syncthreads();
    #pragma unroll 8
    for (int i = wave; i < cnt; i += 16) accB += bf2f(sentIn[(size_t)eidx[i] * 64 + lane]);
  }
  part[wave][0][lane] = accA;
  part[wave][1][lane] = accB;
  __syncthreads();
  if (tid < 128){
    int l = tid & 63, which = tid >> 6;
    float m = 0.f;
    #pragma unroll
    for (int w = 0; w < 16; ++w) m += part[w][which][l];
    float ci = compIn[c * 64 + l];
    if (which == 0) xa[l] = ci + m; else xb[l] = ci + m;
  }
  __syncthreads();
  if (tid < 128){
    int j = tid & 63;
    const float* X  = (tid < 64) ? xa : xb;
    const float* Wt = (tid < 64) ? Wat : Wbt;
    float acc = (tid < 64) ? ba[j] : bb[j];
    #pragma unroll 4
    for (int k = 0; k < 64; ++k) acc += X[k] * Wt[k * 68 + j];
    float al = (tid < 64) ? *aaP : *abP;
    outab[tid] = (acc >= 0.f) ? acc : al * acc;
  }
  __syncthreads();
  if (tid < 64) xa[tid] = outab[tid] + outab[64 + tid];
  __syncthreads();
  if (tid < 128){
    int j = tid >> 6;
    float p = xa[lane] * clsW[j * 64 + lane];
    #pragma unroll
    for (int s = 32; s > 0; s >>= 1) p += __shfl_down(p, s, 64);
    if (lane == 0) outp[c * 2 + j] = p + clsb[j];
  }
}

extern "C" void kernel_launch(void* const* d_in, const int* in_sizes, int n_in,
                              void* d_out, int out_size, void* d_ws, size_t ws_size,
                              hipStream_t stream) {
  (void)in_sizes; (void)n_in; (void)out_size; (void)ws_size;
  const float* company_ts = (const float*)d_in[0];
  const float* sentence_x = (const float*)d_in[1];
  const int*   company_ids = (const int*)d_in[2];
  const int*   c2c_src = (const int*)d_in[3];
  const int*   c2c_dst = (const int*)d_in[4];
  const int*   s2c_src = (const int*)d_in[5];
  const int*   s2c_dst = (const int*)d_in[6];
  const int*   c2s_src = (const int*)d_in[7];
  const int*   c2s_dst = (const int*)d_in[8];
  const float* bn_gamma = (const float*)d_in[9];
  const float* bn_beta  = (const float*)d_in[10];
  const float* Wih0 = (const float*)d_in[11];
  const float* Whh0 = (const float*)d_in[12];
  const float* bih0 = (const float*)d_in[13];
  const float* bhh0 = (const float*)d_in[14];
  const float* Wih1 = (const float*)d_in[15];
  const float* Whh1 = (const float*)d_in[16];
  const float* bih1 = (const float*)d_in[17];
  const float* bhh1 = (const float*)d_in[18];
  const float* fc_W = (const float*)d_in[19];
  const float* fc_b = (const float*)d_in[20];
  const float* comp_emb = (const float*)d_in[21];
  const float* proj_W = (const float*)d_in[22];
  const float* proj_b = (const float*)d_in[23];
  const float* gin_W = (const float*)d_in[24];
  const float* gin_b = (const float*)d_in[25];
  const float* gin_a = (const float*)d_in[26];
  const float* cls_W = (const float*)d_in[27];
  const float* cls_b = (const float*)d_in[28];
  float* outp = (float*)d_out;

  char* ws = (char*)d_ws;
  size_t off = 0;
  auto alloc = [&](size_t bytes)->char* {
    char* r = ws + off;
    off += (bytes + 255) & ~(size_t)255;
    return r;
  };
  float* ts_norm = (float*)alloc((size_t)NCC * TTT * 4);
  float* comp0   = (float*)alloc((size_t)NCC * 64 * 4);
  float* comp1   = (float*)alloc((size_t)NCC * 64 * 4);
  u16*   sent0   = (u16*)alloc((size_t)SSN * 64 * 2);
  u16*   sent1   = (u16*)alloc((size_t)SSN * 64 * 2);
  int*   blockHist = (int*)alloc((size_t)NCC * NB2 * 4);
  int*   colTotal  = (int*)alloc((size_t)NCC * 4);
  int*   cnt_c2c  = (int*)alloc((size_t)ZN * 4);
  int*   cnt2_c2c = cnt_c2c + NCC;
  int*   cnt_c2s  = cnt2_c2c + NCC;
  int*   cnt2_c2s = cnt_c2s + SSN;
  int*   off_c2c = (int*)alloc((size_t)(NCC + 1) * 4);
  int*   off_s2c = (int*)alloc((size_t)(NCC + 1) * 4);
  int*   off_c2s = (int*)alloc((size_t)(SSN + 1) * 4);
  int*   bkt_c2c = (int*)alloc((size_t)ECN * 4);
  int*   bkt_s2c = (int*)alloc((size_t)EEN * 4);
  int*   bkt_c2s = (int*)alloc((size_t)EEN * 4);
  int*   bsum    = (int*)alloc(256 * 4);

  // --- CSR builds + bn ---
  k_zero<<<(ZN + 255) / 256, 256, 0, stream>>>(cnt_c2c, ZN);
  k_histF<<<NB2 + HALLB, 256, 0, stream>>>(s2c_dst, blockHist, c2c_dst, cnt_c2c, c2s_dst, cnt_c2s);
  k_scanA<<<NCC + CSBLK + TTT, 1024, 0, stream>>>(blockHist, colTotal, cnt_c2s, off_c2s, bsum,
                                                  company_ts, bn_gamma, bn_beta, ts_norm);
  k_scanBL<<<1 + CSBLK + LSTMB, 1024, 0, stream>>>(cnt_c2c, off_c2c, colTotal, off_s2c, off_c2s, bsum,
                                                   ts_norm, Wih0, Whh0, bih0, bhh0,
                                                   Wih1, Whh1, bih1, bhh1,
                                                   fc_W, fc_b, comp_emb, company_ids, comp0);
  k_scatF<<<NB2 + HALLB, 256, 0, stream>>>(s2c_src, s2c_dst, blockHist, off_s2c, bkt_s2c,
                                           c2c_src, c2c_dst, off_c2c, cnt2_c2c, bkt_c2c,
                                           c2s_src, c2s_dst, off_c2s, cnt2_c2s, bkt_c2s);

  // --- sentence projection (MFMA) ---
  k_projm<<<(SSN + 127) / 128, 256, 0, stream>>>(sentence_x, proj_W, proj_b, sent0);

  // --- GIN layer 0: company + sentence merged (sent0 -> sent1, comp0 -> comp1) ---
  k_gin0<<<NCC + SGB, 1024, 0, stream>>>(comp0, sent0,
                                         off_c2c, bkt_c2c, off_s2c, bkt_s2c,
                                         off_c2s, bkt_c2s,
                                         gin_W, gin_b, gin_a,
                                         comp1, sent1);

  // --- GIN layer 1 + classifier (layer-1 new_sent is dead code) ---
  k_cgin1<<<NCC, 1024, 0, stream>>>(comp1, sent1,
                                    off_c2c, bkt_c2c, off_s2c, bkt_s2c,
                                    gin_W + 3 * 4096, gin_b + 3 * 64, gin_a + 3,
                                    gin_W + 4 * 4096, gin_b + 4 * 64, gin_a + 4,
                                    cls_W, cls_b, outp);
}

// Round 9
// 552.787 us; speedup vs baseline: 1.1949x; 1.1949x over previous
//
#include <hip/hip_runtime.h>

#define NCC 617
#define TTT 15
#define FFF 5
#define SSN 200000
#define EEN 1000000
#define ECN 20000
#define CSBLK 196   /* ceil(SSN/1024) */
#define NB2 512
#define EPB2 ((EEN + NB2 - 1) / NB2)   /* 1954 */
#define ZN (NCC + NCC + SSN + SSN)
#define HALLB ((ECN + EEN + 255) / 256) /* 3985 */
#define SGB 782     /* ceil(SSN/256) sentence-gin blocks */

typedef unsigned short u16;
typedef unsigned int   u32;

using short8  = __attribute__((ext_vector_type(8))) short;
using f32x4v  = __attribute__((ext_vector_type(4))) float;

__device__ __forceinline__ float bf2f(u16 u){ return __uint_as_float(((u32)u) << 16); }
__device__ __forceinline__ u16 f2bf(float f){
  u32 x = __float_as_uint(f);
  u32 r = (x + 0x7fffu + ((x >> 16) & 1u)) >> 16;
  return (u16)r;
}
__device__ __forceinline__ u32 pk2(float a, float b){ return (u32)f2bf(a) | ((u32)f2bf(b) << 16); }
__device__ __forceinline__ float sigm(float x){ return 1.0f / (1.0f + __expf(-x)); }

// ---------------- zero counters ----------------
__global__ __launch_bounds__(256) void k_zero(int* p, int n){
  int i = blockIdx.x * 256 + threadIdx.x;
  if (i < n) p[i] = 0;
}

// ---------------- fused histograms: s2c LDS block-hist | c2c+c2s global-atomic hist ----------------
__global__ __launch_bounds__(256) void k_histF(const int* __restrict__ s2c_dst, int* __restrict__ blockHist,
                                               const int* __restrict__ c2c_dst, int* __restrict__ cnt_c2c,
                                               const int* __restrict__ c2s_dst, int* __restrict__ cnt_c2s){
  __shared__ int h[NCC];
  int b = blockIdx.x, tid = threadIdx.x;
  if (b < NB2){
    for (int i = tid; i < NCC; i += 256) h[i] = 0;
    __syncthreads();
    int e0 = b * EPB2;
    int e1 = e0 + EPB2; if (e1 > EEN) e1 = EEN;
    for (int e = e0 + tid; e < e1; e += 256) atomicAdd(&h[s2c_dst[e]], 1);
    __syncthreads();
    for (int i = tid; i < NCC; i += 256) blockHist[i * NB2 + b] = h[i];
  } else {
    int i = (b - NB2) * 256 + tid;
    if (i < ECN) atomicAdd(&cnt_c2c[c2c_dst[i]], 1);
    else if (i < ECN + EEN) atomicAdd(&cnt_c2s[c2s_dst[i - ECN]], 1);
  }
}

// ---------------- fused: colscan (617) | c2s block-scan (196) | batchnorm (15) ----------------
__global__ __launch_bounds__(1024) void k_scanA(int* __restrict__ blockHist, int* __restrict__ colTotal,
                                                const int* __restrict__ cnt_c2s, int* __restrict__ off_c2s,
                                                int* __restrict__ bsum,
                                                const float* __restrict__ ts, const float* __restrict__ gamma,
                                                const float* __restrict__ beta, float* __restrict__ tsn){
  __shared__ int buf[1024];
  __shared__ float ss[1024], s2[1024];
  int b = blockIdx.x, tid = threadIdx.x;
  if (b < NCC){
    if (tid < 64){
      int lane = tid;
      int base = 0;
      for (int j = 0; j < NB2; j += 64){
        int v = blockHist[b * NB2 + j + lane];
        int orig = v;
        #pragma unroll
        for (int s = 1; s < 64; s <<= 1){
          int t = __shfl_up(v, s, 64);
          if (lane >= s) v += t;
        }
        blockHist[b * NB2 + j + lane] = base + v - orig;
        base += __shfl(v, 63, 64);
      }
      if (lane == 0) colTotal[b] = base;
    }
  } else if (b < NCC + CSBLK) {
    int bb = b - NCC;
    int gi = bb * 1024 + tid;
    int v = (gi < SSN) ? cnt_c2s[gi] : 0;
    buf[tid] = v;
    __syncthreads();
    for (int d = 1; d < 1024; d <<= 1){
      int x = (tid >= d) ? buf[tid - d] : 0;
      __syncthreads();
      buf[tid] += x;
      __syncthreads();
    }
    if (gi < SSN) off_c2s[gi] = buf[tid] - v;
    if (tid == 1023) bsum[bb] = buf[1023];
  } else {
    int t = b - (NCC + CSBLK);
    float a = 0.f, s = 0.f;
    for (int c = tid; c < NCC; c += 1024){
      float v = ts[(c * TTT + t) * FFF + 3];
      a += v; s += v * v;
    }
    ss[tid] = a; s2[tid] = s;
    __syncthreads();
    for (int d = 512; d > 0; d >>= 1){
      if (tid < d){ ss[tid] += ss[tid + d]; s2[tid] += s2[tid + d]; }
      __syncthreads();
    }
    float mean = ss[0] / (float)NCC;
    float var  = s2[0] / (float)NCC - mean * mean;
    float rstd = rsqrtf(var + 1e-5f);
    float g = gamma[t], be = beta[t];
    for (int c = tid; c < NCC; c += 1024){
      float v = ts[(c * TTT + t) * FFF + 3];
      tsn[c * TTT + t] = (v - mean) * rstd * g + be;
    }
  }
}

// ---------------- fused: dual 617-scan (block 0) | c2s scan-add (blocks 1..196) ----------------
__global__ __launch_bounds__(1024) void k_scanB(const int* __restrict__ cnt_c2c, int* __restrict__ off_c2c,
                                                const int* __restrict__ colTotal, int* __restrict__ off_s2c,
                                                int* __restrict__ off_c2s, const int* __restrict__ bsum){
  __shared__ int buf[1024];
  __shared__ int sboff[CSBLK + 1];
  int b = blockIdx.x, tid = threadIdx.x;
  if (b == 0){
    for (int pass = 0; pass < 2; ++pass){
      const int* cnt = pass ? colTotal : cnt_c2c;
      int* ofs = pass ? off_s2c : off_c2c;
      int v = (tid < NCC) ? cnt[tid] : 0;
      buf[tid] = v;
      __syncthreads();
      for (int d = 1; d < 1024; d <<= 1){
        int x = (tid >= d) ? buf[tid - d] : 0;
        __syncthreads();
        buf[tid] += x;
        __syncthreads();
      }
      if (tid < NCC) ofs[tid] = (tid == 0) ? 0 : buf[tid - 1];
      if (tid == 0) ofs[NCC] = buf[NCC - 1];
      __syncthreads();
    }
  } else {
    int bb = b - 1;
    int lane = tid & 63;
    if (tid < 64){
      int base = 0;
      for (int j = 0; j < CSBLK; j += 64){
        int idx = j + lane;
        int v = (idx < CSBLK) ? bsum[idx] : 0;
        int orig = v;
        #pragma unroll
        for (int s = 1; s < 64; s <<= 1){
          int t2 = __shfl_up(v, s, 64);
          if (lane >= s) v += t2;
        }
        if (idx < CSBLK) sboff[idx] = base + v - orig;
        base += __shfl(v, 63, 64);
      }
      if (lane == 0) sboff[CSBLK] = base;
    }
    __syncthreads();
    int gi = bb * 1024 + tid;
    if (gi < SSN) off_c2s[gi] += sboff[bb];
    if (bb == 0 && tid == 0) off_c2s[SSN] = sboff[CSBLK];
  }
}

// ---------------- fused scatter ----------------
__global__ __launch_bounds__(256) void k_scatF(const int* __restrict__ s2c_src, const int* __restrict__ s2c_dst,
                                               const int* __restrict__ blockHist, const int* __restrict__ off_s2c,
                                               int* __restrict__ bkt_s2c,
                                               const int* __restrict__ c2c_src, const int* __restrict__ c2c_dst,
                                               const int* __restrict__ off_c2c, int* __restrict__ cnt2_c2c,
                                               int* __restrict__ bkt_c2c,
                                               const int* __restrict__ c2s_src, const int* __restrict__ c2s_dst,
                                               const int* __restrict__ off_c2s, int* __restrict__ cnt2_c2s,
                                               int* __restrict__ bkt_c2s){
  __shared__ int cur[NCC];
  int b = blockIdx.x, tid = threadIdx.x;
  if (b < NB2){
    for (int i = tid; i < NCC; i += 256) cur[i] = off_s2c[i] + blockHist[i * NB2 + b];
    __syncthreads();
    int e0 = b * EPB2;
    int e1 = e0 + EPB2; if (e1 > EEN) e1 = EEN;
    for (int e = e0 + tid; e < e1; e += 256){
      int d = s2c_dst[e];
      int p = atomicAdd(&cur[d], 1);
      bkt_s2c[p] = s2c_src[e];
    }
  } else {
    int i = (b - NB2) * 256 + tid;
    if (i < ECN){
      int d = c2c_dst[i]; int p = off_c2c[d] + atomicAdd(&cnt2_c2c[d], 1); bkt_c2c[p] = c2c_src[i];
    } else if (i < ECN + EEN){
      int k = i - ECN;
      int d = c2s_dst[k]; int p = off_c2s[d] + atomicAdd(&cnt2_c2s[d], 1); bkt_c2s[p] = c2s_src[k];
    }
  }
}

// ---------------- fused 2-layer LSTM + fc + emb ----------------
__global__ __launch_bounds__(256, 1) void k_lstm01(const float* __restrict__ tsn,
                                                   const float* __restrict__ Wih0, const float* __restrict__ Whh0,
                                                   const float* __restrict__ bih0, const float* __restrict__ bhh0,
                                                   const float* __restrict__ Wih1, const float* __restrict__ Whh1,
                                                   const float* __restrict__ bih1, const float* __restrict__ bhh1,
                                                   const float* __restrict__ fcW, const float* __restrict__ fcb,
                                                   const float* __restrict__ emb, const int* __restrict__ ids,
                                                   float* __restrict__ comp0){
  __shared__ __align__(16) u16 sW0[64 * 64 * 4];
  __shared__ __align__(16) u16 sP1[64 * 64 * 8];
  __shared__ float sWi[256];
  __shared__ float sB0[256];
  int tid = threadIdx.x;
  for (int i = tid; i < 16384; i += 256){
    int k = i >> 8, j = (i >> 2) & 63, g = i & 3;
    sW0[i] = f2bf(Whh0[(g * 64 + j) * 64 + k]);
  }
  for (int i = tid; i < 32768; i += 256){
    int k = i >> 9, j = (i >> 3) & 63, g = i & 7;
    float v = (g < 4) ? Wih1[(g * 64 + j) * 64 + k] : Whh1[((g - 4) * 64 + j) * 64 + k];
    sP1[i] = f2bf(v);
  }
  sWi[tid] = Wih0[tid];
  sB0[tid] = bih0[tid] + bhh0[tid];
  __syncthreads();
  int wave = tid >> 6, lane = tid & 63;
  int c = blockIdx.x * 4 + wave;
  int ci = (c < NCC) ? c : (NCC - 1);
  float wi_i = sWi[lane], wi_f = sWi[64 + lane], wi_g = sWi[128 + lane], wi_o = sWi[192 + lane];
  float b0i = sB0[lane], b0f = sB0[64 + lane], b0g = sB0[128 + lane], b0o = sB0[192 + lane];
  float b1i = bih1[lane]       + bhh1[lane];
  float b1f = bih1[64 + lane]  + bhh1[64 + lane];
  float b1g = bih1[128 + lane] + bhh1[128 + lane];
  float b1o = bih1[192 + lane] + bhh1[192 + lane];
  float h0 = 0.f, c0 = 0.f, h1 = 0.f, c1 = 0.f;
  for (int t = 0; t < TTT; ++t){
    float x = tsn[ci * TTT + t];
    float gi = b0i + x * wi_i, gf = b0f + x * wi_f, gg = b0g + x * wi_g, go = b0o + x * wi_o;
    #pragma unroll 4
    for (int k = 0; k < 64; ++k){
      float hk = __shfl(h0, k, 64);
      ushort4 w = *(const ushort4*)&sW0[(k * 64 + lane) * 4];
      gi += hk * bf2f(w.x); gf += hk * bf2f(w.y);
      gg += hk * bf2f(w.z); go += hk * bf2f(w.w);
    }
    c0 = sigm(gf) * c0 + sigm(gi) * tanhf(gg);
    h0 = sigm(go) * tanhf(c0);
    gi = b1i; gf = b1f; gg = b1g; go = b1o;
    #pragma unroll 4
    for (int k = 0; k < 64; ++k){
      float xk = __shfl(h0, k, 64);
      float hk = __shfl(h1, k, 64);
      short8 wv = *(const short8*)&sP1[(k * 64 + lane) * 8];
      gi += xk * bf2f((u16)wv[0]) + hk * bf2f((u16)wv[4]);
      gf += xk * bf2f((u16)wv[1]) + hk * bf2f((u16)wv[5]);
      gg += xk * bf2f((u16)wv[2]) + hk * bf2f((u16)wv[6]);
      go += xk * bf2f((u16)wv[3]) + hk * bf2f((u16)wv[7]);
    }
    c1 = sigm(gf) * c1 + sigm(gi) * tanhf(gg);
    h1 = sigm(go) * tanhf(c1);
  }
  __syncthreads();
  float* fws = (float*)sW0;
  for (int i = tid; i < 4096; i += 256){
    int d = i >> 6, k = i & 63;
    fws[k * 64 + d] = fcW[i];
  }
  __syncthreads();
  float y = fcb[lane];
  #pragma unroll 4
  for (int k = 0; k < 64; ++k){
    float hk = __shfl(h1, k, 64);
    y += hk * fws[k * 64 + lane];
  }
  y = fmaxf(y, 0.f);
  if (c < NCC) comp0[c * 64 + lane] = y + emb[ids[c] * 64 + lane];
}

// ---------------- proj GEMM via MFMA ----------------
__global__ __launch_bounds__(256) void k_projm(const float* __restrict__ A, const float* __restrict__ W,
                                               const float* __restrict__ pb, u16* __restrict__ sent0){
  __shared__ __align__(16) u16 sA[128 * 64];
  __shared__ __align__(16) u16 sB[64 * 64];
  char* sAb = (char*)sA;
  char* sBb = (char*)sB;
  int tid = threadIdx.x;
  int wave = tid >> 6, lane = tid & 63;
  int l15 = lane & 15, lg = lane >> 4;
  int s0 = blockIdx.x * 128;

  int rA = tid >> 1, hA = tid & 1;
  int sA_row = s0 + rA; if (sA_row >= SSN) sA_row = SSN - 1;
  const float* gA0 = &A[(size_t)sA_row * 768 + hA * 32];
  u32 aw_base = (u32)(rA * 128 + hA * 64);
  u32 aw_swz  = (u32)((rA & 7) << 4);
  int nB = tid >> 2, qB = tid & 3;
  const float* gB0 = &W[(size_t)nB * 768 + qB * 16];
  u32 bw_base = (u32)(nB * 128 + qB * 32);
  u32 bw_swz  = (u32)((nB & 7) << 4);

  int arow = wave * 32 + l15;
  u32 ar_swz = (u32)((arow & 7) << 4);
  u32 ar_base = (u32)(arow * 128 + lg * 16);
  u32 br_swz = (u32)((l15 & 7) << 4);
  u32 br_base = (u32)(l15 * 128 + lg * 16);

  f32x4v acc[2][4] = {};

  for (int kc = 0; kc < 12; ++kc){
    __syncthreads();
    {
      const float* g = gA0 + kc * 64;
      #pragma unroll
      for (int q = 0; q < 4; ++q){
        float4 va = ((const float4*)g)[2 * q];
        float4 vb = ((const float4*)g)[2 * q + 1];
        uint4 w;
        w.x = pk2(va.x, va.y); w.y = pk2(va.z, va.w);
        w.z = pk2(vb.x, vb.y); w.w = pk2(vb.z, vb.w);
        *(uint4*)(sAb + ((aw_base + q * 16) ^ aw_swz)) = w;
      }
    }
    {
      const float* g = gB0 + kc * 64;
      #pragma unroll
      for (int q = 0; q < 2; ++q){
        float4 va = ((const float4*)g)[2 * q];
        float4 vb = ((const float4*)g)[2 * q + 1];
        uint4 w;
        w.x = pk2(va.x, va.y); w.y = pk2(va.z, va.w);
        w.z = pk2(vb.x, vb.y); w.w = pk2(vb.z, vb.w);
        *(uint4*)(sBb + ((bw_base + q * 16) ^ bw_swz)) = w;
      }
    }
    __syncthreads();
    #pragma unroll
    for (int ks = 0; ks < 2; ++ks){
      short8 a0 = *(const short8*)(sAb + ((ar_base + 0    + ks * 64) ^ ar_swz));
      short8 a1 = *(const short8*)(sAb + ((ar_base + 2048 + ks * 64) ^ ar_swz));
      short8 b0 = *(const short8*)(sBb + ((br_base + 0    + ks * 64) ^ br_swz));
      short8 b1 = *(const short8*)(sBb + ((br_base + 2048 + ks * 64) ^ br_swz));
      short8 b2 = *(const short8*)(sBb + ((br_base + 4096 + ks * 64) ^ br_swz));
      short8 b3 = *(const short8*)(sBb + ((br_base + 6144 + ks * 64) ^ br_swz));
      acc[0][0] = __builtin_amdgcn_mfma_f32_16x16x32_bf16(a0, b0, acc[0][0], 0, 0, 0);
      acc[0][1] = __builtin_amdgcn_mfma_f32_16x16x32_bf16(a0, b1, acc[0][1], 0, 0, 0);
      acc[0][2] = __builtin_amdgcn_mfma_f32_16x16x32_bf16(a0, b2, acc[0][2], 0, 0, 0);
      acc[0][3] = __builtin_amdgcn_mfma_f32_16x16x32_bf16(a0, b3, acc[0][3], 0, 0, 0);
      acc[1][0] = __builtin_amdgcn_mfma_f32_16x16x32_bf16(a1, b0, acc[1][0], 0, 0, 0);
      acc[1][1] = __builtin_amdgcn_mfma_f32_16x16x32_bf16(a1, b1, acc[1][1], 0, 0, 0);
      acc[1][2] = __builtin_amdgcn_mfma_f32_16x16x32_bf16(a1, b2, acc[1][2], 0, 0, 0);
      acc[1][3] = __builtin_amdgcn_mfma_f32_16x16x32_bf16(a1, b3, acc[1][3], 0, 0, 0);
    }
  }

  float bias[4];
  #pragma unroll
  for (int nt = 0; nt < 4; ++nt) bias[nt] = pb[nt * 16 + l15];
  #pragma unroll
  for (int mt = 0; mt < 2; ++mt){
    #pragma unroll
    for (int j = 0; j < 4; ++j){
      int s = s0 + wave * 32 + mt * 16 + lg * 4 + j;
      if (s < SSN){
        #pragma unroll
        for (int nt = 0; nt < 4; ++nt)
          sent0[(size_t)s * 64 + nt * 16 + l15] = f2bf(acc[mt][nt][j] + bias[nt]);
      }
    }
  }
}

// ---------------- merged GIN layer 0 ----------------
__global__ __launch_bounds__(1024) void k_gin0(const float* __restrict__ compIn, const u16* __restrict__ sentIn,
                                               const int* __restrict__ ofsA, const int* __restrict__ bktA,
                                               const int* __restrict__ ofsB, const int* __restrict__ bktB,
                                               const int* __restrict__ ofsS, const int* __restrict__ bktS,
                                               const float* __restrict__ gin_W, const float* __restrict__ gin_b,
                                               const float* __restrict__ gin_a,
                                               float* __restrict__ compOut, u16* __restrict__ sentOut){
  __shared__ __align__(16) char smem[52224];
  int tid = threadIdx.x;
  int wave = tid >> 6, lane = tid & 63;
  int b = blockIdx.x;
  if (b < NCC){
    float* Wat  = (float*)smem;
    float* Wbt  = Wat + 64 * 68;
    int*   eidx = (int*)(Wbt + 64 * 68);
    float* part = (float*)(eidx + 2048);
    float* xa   = part + 2048;
    float* xb   = xa + 64;
    float* outab = xb + 64;
    const float* Wa = gin_W + 0 * 4096;
    const float* Wb = gin_W + 1 * 4096;
    for (int i = tid; i < 4096; i += 1024){
      int j = i >> 6, k = i & 63;
      Wat[k * 68 + j] = Wa[i];
      Wbt[k * 68 + j] = Wb[i];
    }
    int c = b;
    float accA = 0.f, accB = 0.f;
    int a0 = ofsA[c], a1 = ofsA[c + 1];
    for (int base = a0; base < a1; base += 2048){
      int cnt = a1 - base; if (cnt > 2048) cnt = 2048;
      __syncthreads();
      for (int i = tid; i < cnt; i += 1024) eidx[i] = bktA[base + i];
      __syncthreads();
      #pragma unroll 4
      for (int i = wave; i < cnt; i += 16) accA += compIn[eidx[i] * 64 + lane];
    }
    int b0 = ofsB[c], b1 = ofsB[c + 1];
    for (int base = b0; base < b1; base += 2048){
      int cnt = b1 - base; if (cnt > 2048) cnt = 2048;
      __syncthreads();
      for (int i = tid; i < cnt; i += 1024) eidx[i] = bktB[base + i];
      __syncthreads();
      #pragma unroll 8
      for (int i = wave; i < cnt; i += 16) accB += bf2f(sentIn[(size_t)eidx[i] * 64 + lane]);
    }
    part[(wave * 2 + 0) * 64 + lane] = accA;
    part[(wave * 2 + 1) * 64 + lane] = accB;
    __syncthreads();
    if (tid < 128){
      int l = tid & 63, which = tid >> 6;
      float m = 0.f;
      #pragma unroll
      for (int w = 0; w < 16; ++w) m += part[(w * 2 + which) * 64 + l];
      float ci = compIn[c * 64 + l];
      if (which == 0) xa[l] = ci + m; else xb[l] = ci + m;
    }
    __syncthreads();
    if (tid < 128){
      int j = tid & 63;
      const float* X  = (tid < 64) ? xa : xb;
      const float* Wt = (tid < 64) ? Wat : Wbt;
      float acc = (tid < 64) ? gin_b[j] : gin_b[64 + j];
      #pragma unroll 4
      for (int k = 0; k < 64; ++k) acc += X[k] * Wt[k * 68 + j];
      float al = (tid < 64) ? gin_a[0] : gin_a[1];
      outab[tid] = (acc >= 0.f) ? acc : al * acc;
    }
    __syncthreads();
    if (tid < 64) compOut[c * 64 + tid] = outab[tid] + outab[64 + tid];
  } else {
    u16* sX   = (u16*)smem;
    u16* sW   = sX + 16384;
    int* eb   = (int*)(sW + 4096);
    int* sofs = eb + 2048;
    char* sXb = (char*)sX;
    char* sWb = (char*)sW;
    const float* W = gin_W + 2 * 4096;
    const float* bi = gin_b + 128;
    {
      int n = tid >> 4, q = tid & 15;
      float4 v = *(const float4*)&W[n * 64 + q * 4];
      uint2 w;
      w.x = pk2(v.x, v.y); w.y = pk2(v.z, v.w);
      *(uint2*)(sWb + (((u32)(n * 128 + q * 8)) ^ ((u32)((n & 7) << 4)))) = w;
    }
    int sBase = (b - NCC) * 256;
    if (tid < 257){
      int idx = sBase + tid; if (idx > SSN) idx = SSN;
      sofs[tid] = ofsS[idx];
    }
    __syncthreads();
    int E0 = sofs[0];
    int tot = sofs[256] - E0;
    int staged = tot < 2048 ? tot : 2048;
    for (int i = tid; i < staged; i += 1024) eb[i] = bktS[E0 + i];
    __syncthreads();
    for (int q = 0; q < 16; ++q){
      int sL = wave * 16 + q;
      int s = sBase + sL;
      if (s < SSN){
        float acc = bf2f(sentIn[(size_t)s * 64 + lane]);
        int e0 = sofs[sL], e1 = sofs[sL + 1];
        for (int e = e0; e < e1; ++e){
          int r = e - E0;
          int src = (r < 2048) ? eb[r] : bktS[e];
          acc += compIn[src * 64 + lane];
        }
        *(u16*)(sXb + (((u32)(sL * 128 + lane * 2)) ^ ((u32)((sL & 7) << 4)))) = f2bf(acc);
      }
    }
    __syncthreads();
    int l15 = lane & 15, lg = lane >> 4;
    int arow = wave * 16 + l15;
    u32 ar_swz = (u32)((arow & 7) << 4);
    u32 br_swz = (u32)((l15 & 7) << 4);
    f32x4v acc4[4] = {};
    #pragma unroll
    for (int ks = 0; ks < 2; ++ks){
      short8 a0 = *(const short8*)(sXb + (((u32)(arow * 128 + ks * 64 + lg * 16)) ^ ar_swz));
      #pragma unroll
      for (int nt = 0; nt < 4; ++nt){
        short8 b0 = *(const short8*)(sWb + (((u32)((nt * 16 + l15) * 128 + ks * 64 + lg * 16)) ^ br_swz));
        acc4[nt] = __builtin_amdgcn_mfma_f32_16x16x32_bf16(a0, b0, acc4[nt], 0, 0, 0);
      }
    }
    float alpha = gin_a[2];
    #pragma unroll
    for (int nt = 0; nt < 4; ++nt){
      float bb = bi[nt * 16 + l15];
      #pragma unroll
      for (int j = 0; j < 4; ++j){
        int srow = sBase + wave * 16 + lg * 4 + j;
        if (srow < SSN){
          float h = acc4[nt][j] + bb;
          h = (h >= 0.f) ? h : alpha * h;
          sentOut[(size_t)srow * 64 + nt * 16 + l15] = f2bf(h);
        }
      }
    }
  }
}

// ---------------- company GIN layer 1 + fused classifier ----------------
__global__ __launch_bounds__(1024) void k_cgin1(const float* __restrict__ compIn, const u16* __restrict__ sentIn,
                                                const int* __restrict__ ofsA, const int* __restrict__ bktA,
                                                const int* __restrict__ ofsB, const int* __restrict__ bktB,
                                                const float* __restrict__ Wa, const float* __restrict__ ba, const float* aaP,
                                                const float* __restrict__ Wb, const float* __restrict__ bb, const float* abP,
                                                const float* __restrict__ clsW, const float* __restrict__ clsb,
                                                float* __restrict__ outp){
  __shared__ __align__(16) float Wat[64 * 68];
  __shared__ __align__(16) float Wbt[64 * 68];
  __shared__ int eidx[2048];
  __shared__ float part[16][2][64];
  __shared__ float xa[64], xb[64], outab[128];
  int tid = threadIdx.x;
  for (int i = tid; i < 4096; i += 1024){
    int j = i >> 6, k = i & 63;
    Wat[k * 68 + j] = Wa[i];
    Wbt[k * 68 + j] = Wb[i];
  }
  int wave = tid >> 6, lane = tid & 63;
  int c = blockIdx.x;
  float accA = 0.f, accB = 0.f;
  int a0 = ofsA[c], a1 = ofsA[c + 1];
  for (int base = a0; base < a1; base += 2048){
    int cnt = a1 - base; if (cnt > 2048) cnt = 2048;
    __syncthreads();
    for (int i = tid; i < cnt; i += 1024) eidx[i] = bktA[base + i];
    __syncthreads();
    #pragma unroll 4
    for (int i = wave; i < cnt; i += 16) accA += compIn[eidx[i] * 64 + lane];
  }
  int b0 = ofsB[c], b1 = ofsB[c + 1];
  for (int base = b0; base < b1; base += 2048){
    int cnt = b1 - base; if (cnt > 2048) cnt = 2048;
    __syncthreads();
    for (int i = tid; i < cnt; i += 1024) eidx[i] = bktB[base + i];
    __syncthreads();
    #pragma unroll 8
    for (int i = wave; i < cnt; i += 16) accB += bf2f(sentIn[(size_t)eidx[i] * 64 + lane]);
  }
  part[wave][0][lane] = accA;
  part[wave][1][lane] = accB;
  __syncthreads();
  if (tid < 128){
    int l = tid & 63, which = tid >> 6;
    float m = 0.f;
    #pragma unroll
    for (int w = 0; w < 16; ++w) m += part[w][which][l];
    float ci = compIn[c * 64 + l];
    if (which == 0) xa[l] = ci + m; else xb[l] = ci + m;
  }
  __syncthreads();
  if (tid < 128){
    int j = tid & 63;
    const float* X  = (tid < 64) ? xa : xb;
    const float* Wt = (tid < 64) ? Wat : Wbt;
    float acc = (tid < 64) ? ba[j] : bb[j];
    #pragma unroll 4
    for (int k = 0; k < 64; ++k) acc += X[k] * Wt[k * 68 + j];
    float al = (tid < 64) ? *aaP : *abP;
    outab[tid] = (acc >= 0.f) ? acc : al * acc;
  }
  __syncthreads();
  if (tid < 64) xa[tid] = outab[tid] + outab[64 + tid];
  __syncthreads();
  if (tid < 128){
    int j = tid >> 6;
    float p = xa[lane] * clsW[j * 64 + lane];
    #pragma unroll
    for (int s = 32; s > 0; s >>= 1) p += __shfl_down(p, s, 64);
    if (lane == 0) outp[c * 2 + j] = p + clsb[j];
  }
}

extern "C" void kernel_launch(void* const* d_in, const int* in_sizes, int n_in,
                              void* d_out, int out_size, void* d_ws, size_t ws_size,
                              hipStream_t stream) {
  (void)in_sizes; (void)n_in; (void)out_size; (void)ws_size;
  const float* company_ts = (const float*)d_in[0];
  const float* sentence_x = (const float*)d_in[1];
  const int*   company_ids = (const int*)d_in[2];
  const int*   c2c_src = (const int*)d_in[3];
  const int*   c2c_dst = (const int*)d_in[4];
  const int*   s2c_src = (const int*)d_in[5];
  const int*   s2c_dst = (const int*)d_in[6];
  const int*   c2s_src = (const int*)d_in[7];
  const int*   c2s_dst = (const int*)d_in[8];
  const float* bn_gamma = (const float*)d_in[9];
  const float* bn_beta  = (const float*)d_in[10];
  const float* Wih0 = (const float*)d_in[11];
  const float* Whh0 = (const float*)d_in[12];
  const float* bih0 = (const float*)d_in[13];
  const float* bhh0 = (const float*)d_in[14];
  const float* Wih1 = (const float*)d_in[15];
  const float* Whh1 = (const float*)d_in[16];
  const float* bih1 = (const float*)d_in[17];
  const float* bhh1 = (const float*)d_in[18];
  const float* fc_W = (const float*)d_in[19];
  const float* fc_b = (const float*)d_in[20];
  const float* comp_emb = (const float*)d_in[21];
  const float* proj_W = (const float*)d_in[22];
  const float* proj_b = (const float*)d_in[23];
  const float* gin_W = (const float*)d_in[24];
  const float* gin_b = (const float*)d_in[25];
  const float* gin_a = (const float*)d_in[26];
  const float* cls_W = (const float*)d_in[27];
  const float* cls_b = (const float*)d_in[28];
  float* outp = (float*)d_out;

  char* ws = (char*)d_ws;
  size_t off = 0;
  auto alloc = [&](size_t bytes)->char* {
    char* r = ws + off;
    off += (bytes + 255) & ~(size_t)255;
    return r;
  };
  float* ts_norm = (float*)alloc((size_t)NCC * TTT * 4);
  float* comp0   = (float*)alloc((size_t)NCC * 64 * 4);
  float* comp1   = (float*)alloc((size_t)NCC * 64 * 4);
  u16*   sent0   = (u16*)alloc((size_t)SSN * 64 * 2);
  u16*   sent1   = (u16*)alloc((size_t)SSN * 64 * 2);
  int*   blockHist = (int*)alloc((size_t)NCC * NB2 * 4);
  int*   colTotal  = (int*)alloc((size_t)NCC * 4);
  int*   cnt_c2c  = (int*)alloc((size_t)ZN * 4);
  int*   cnt2_c2c = cnt_c2c + NCC;
  int*   cnt_c2s  = cnt2_c2c + NCC;
  int*   cnt2_c2s = cnt_c2s + SSN;
  int*   off_c2c = (int*)alloc((size_t)(NCC + 1) * 4);
  int*   off_s2c = (int*)alloc((size_t)(NCC + 1) * 4);
  int*   off_c2s = (int*)alloc((size_t)(SSN + 1) * 4);
  int*   bkt_c2c = (int*)alloc((size_t)ECN * 4);
  int*   bkt_s2c = (int*)alloc((size_t)EEN * 4);
  int*   bkt_c2s = (int*)alloc((size_t)EEN * 4);
  int*   bsum    = (int*)alloc(256 * 4);

  // --- CSR builds + bn ---
  k_zero<<<(ZN + 255) / 256, 256, 0, stream>>>(cnt_c2c, ZN);
  k_histF<<<NB2 + HALLB, 256, 0, stream>>>(s2c_dst, blockHist, c2c_dst, cnt_c2c, c2s_dst, cnt_c2s);
  k_scanA<<<NCC + CSBLK + TTT, 1024, 0, stream>>>(blockHist, colTotal, cnt_c2s, off_c2s, bsum,
                                                  company_ts, bn_gamma, bn_beta, ts_norm);
  k_scanB<<<1 + CSBLK, 1024, 0, stream>>>(cnt_c2c, off_c2c, colTotal, off_s2c, off_c2s, bsum);
  k_scatF<<<NB2 + HALLB, 256, 0, stream>>>(s2c_src, s2c_dst, blockHist, off_s2c, bkt_s2c,
                                           c2c_src, c2c_dst, off_c2c, cnt2_c2c, bkt_c2c,
                                           c2s_src, c2s_dst, off_c2s, cnt2_c2s, bkt_c2s);

  // --- time-series branch ---
  k_lstm01<<<(NCC + 3) / 4, 256, 0, stream>>>(ts_norm, Wih0, Whh0, bih0, bhh0,
                                              Wih1, Whh1, bih1, bhh1,
                                              fc_W, fc_b, comp_emb, company_ids, comp0);

  // --- sentence projection (MFMA) ---
  k_projm<<<(SSN + 127) / 128, 256, 0, stream>>>(sentence_x, proj_W, proj_b, sent0);

  // --- GIN layer 0: company + sentence merged (sent0 -> sent1, comp0 -> comp1) ---
  k_gin0<<<NCC + SGB, 1024, 0, stream>>>(comp0, sent0,
                                         off_c2c, bkt_c2c, off_s2c, bkt_s2c,
                                         off_c2s, bkt_c2s,
                                         gin_W, gin_b, gin_a,
                                         comp1, sent1);

  // --- GIN layer 1 + classifier (layer-1 new_sent is dead code) ---
  k_cgin1<<<NCC, 1024, 0, stream>>>(comp1, sent1,
                                    off_c2c, bkt_c2c, off_s2c, bkt_s2c,
                                    gin_W + 3 * 4096, gin_b + 3 * 64, gin_a + 3,
                                    gin_W + 4 * 4096, gin_b + 4 * 64, gin_a + 4,
                                    cls_W, cls_b, outp);
}